// Round 3
// baseline (273.671 us; speedup 1.0000x reference)
//
#include <hip/hip_runtime.h>
#include <hip/hip_bf16.h>

#define NROW 8192
#define FIN  512
#define FOUT 64
#define NHEAD 4

constexpr float LOG2E = 1.44269504088896f;

typedef float f32x4 __attribute__((ext_vector_type(4)));
typedef __bf16 bf16x8 __attribute__((ext_vector_type(8)));

// ---------------------------------------------------------------------------
// K0: WT[hd][o][f] = bf16(W[hd][f][o])
// ---------------------------------------------------------------------------
__global__ __launch_bounds__(256) void wt_build(
    const float* __restrict__ W, __hip_bfloat16* __restrict__ WT)
{
  int t = blockIdx.x * 256 + threadIdx.x;       // 2048 threads = 4 heads x 512 f
  int hd = t >> 9, f = t & 511;
  const float* wp = W + (hd * FIN + f) * FOUT;
#pragma unroll 8
  for (int o = 0; o < FOUT; ++o)
    WT[(hd * FOUT + o) * FIN + f] = __float2bfloat16(wp[o]);
}

// ---------------------------------------------------------------------------
// K1: h = x*W via MFMA. Wave = head; block covers 16 rows.
// Emits hT (bf16 [hd][o][n]), f1c = (h.a1)*LOG2E, and per-column exp tables
// E2 = exp2(f2c), D2 = exp2(0.2*f2c).
// ---------------------------------------------------------------------------
__global__ __launch_bounds__(256) void gat_proj(
    const float* __restrict__ x, const __hip_bfloat16* __restrict__ WT,
    const float* __restrict__ a1, const float* __restrict__ a2,
    __hip_bfloat16* __restrict__ hT, float* __restrict__ f1,
    float* __restrict__ E2, float* __restrict__ D2)
{
  const int tid = threadIdx.x;
  const int hd = tid >> 6, lane = tid & 63;
  const int il = lane & 15, kg = lane >> 4;
  const int n0 = blockIdx.x * 16;
  const __hip_bfloat16* wtp = WT + hd * (FOUT * FIN);
  const float* xp = x + (n0 + il) * FIN + kg * 8;

  f32x4 acc[4];
#pragma unroll
  for (int c = 0; c < 4; ++c) { f32x4 z = {0.f,0.f,0.f,0.f}; acc[c] = z; }

#pragma unroll 2
  for (int kk = 0; kk < FIN / 32; ++kk) {
    bf16x8 af[4];
#pragma unroll
    for (int c = 0; c < 4; ++c)
      af[c] = *(const bf16x8*)(wtp + (c * 16 + il) * FIN + kk * 32 + kg * 8);
    f32x4 xl = *(const f32x4*)(xp + kk * 32);
    f32x4 xh = *(const f32x4*)(xp + kk * 32 + 4);
    bf16x8 xb;
#pragma unroll
    for (int e = 0; e < 4; ++e) {
      xb[e]     = (__bf16)xl[e];
      xb[4 + e] = (__bf16)xh[e];
    }
#pragma unroll
    for (int c = 0; c < 4; ++c)
      acc[c] = __builtin_amdgcn_mfma_f32_16x16x32_bf16(af[c], xb, acc[c], 0, 0, 0);
  }

  const int n = n0 + il;
  float p1 = 0.f, p2 = 0.f;
#pragma unroll
  for (int c = 0; c < 4; ++c) {
    f32x4 a1v = *(const f32x4*)(a1 + hd * FOUT + c * 16 + kg * 4);
    f32x4 a2v = *(const f32x4*)(a2 + hd * FOUT + c * 16 + kg * 4);
#pragma unroll
    for (int r = 0; r < 4; ++r) {
      float hv = acc[c][r];
      hT[(hd * FOUT + c * 16 + kg * 4 + r) * NROW + n] = __float2bfloat16(hv);
      p1 = fmaf(hv, a1v[r], p1);
      p2 = fmaf(hv, a2v[r], p2);
    }
  }
  p1 += __shfl_xor(p1, 16); p1 += __shfl_xor(p1, 32);
  p2 += __shfl_xor(p2, 16); p2 += __shfl_xor(p2, 32);
  if (kg == 0) {
    float f1c = p1 * LOG2E;
    float f2c = p2 * LOG2E;
    f1[hd * NROW + n] = f1c;
    E2[hd * NROW + n] = __builtin_amdgcn_exp2f(f2c);
    D2[hd * NROW + n] = __builtin_amdgcn_exp2f(0.2f * f2c);
  }
}

// ---------------------------------------------------------------------------
// K2: pack adj into bitmasks  mw[w = m/32][n]
// ---------------------------------------------------------------------------
__global__ __launch_bounds__(256) void mask_build(
    const int* __restrict__ adj, unsigned int* __restrict__ mw)
{
  const int wid = threadIdx.x >> 6, lane = threadIdx.x & 63;
  const int nrow = blockIdx.x * 4 + wid;
  const int* ap = adj + (size_t)nrow * NROW;
#pragma unroll 4
  for (int it = 0; it < NROW / 64; ++it) {
    unsigned long long b = __ballot(ap[it * 64 + lane] != 0);
    if (lane == 0) {
      mw[(it * 2) * NROW + nrow]     = (unsigned int)b;
      mw[(it * 2 + 1) * NROW + nrow] = (unsigned int)(b >> 32);
    }
  }
}

// ---------------------------------------------------------------------------
// K3: attention partials, exp-free inner loop.
//   s<0  <=>  E2[m] < exp2(-f1c[n]);  p = mask & (s<0 ? D1*D2 : E1*E2)
// Block = 4 waves, same head, 64 rows, m-chunk NROW/S. hT tile [64o][64m]
// in XOR-swizzled LDS (16B unit ^= row&7), double-buffered, 1 barrier/iter.
// ---------------------------------------------------------------------------
template <int S>
__global__ __launch_bounds__(256, 4) void gat_attn(
    const unsigned int* __restrict__ mw, const __hip_bfloat16* __restrict__ hTg,
    const float* __restrict__ f1, const float* __restrict__ E2g,
    const float* __restrict__ D2g, float* __restrict__ part)
{
  constexpr int MCH = NROW / S;
  constexpr int ITERS = MCH / 64;
  const int tid = threadIdx.x;
  const int wid = tid >> 6, lane = tid & 63;
  const int il = lane & 15, kg = lane >> 4;

  // XCD-chunked block swizzle (grid % 8 == 0): each XCD gets a contiguous
  // logical range -> few hT panels per XCD L2.
  const int nwg = S * NHEAD * 128;
  const int bid = (blockIdx.x & 7) * (nwg >> 3) + (blockIdx.x >> 3);
  const int rg = bid & 127;
  const int hd = (bid >> 7) & 3;
  const int mc = bid >> 9;
  const int n0 = rg * 64;
  const int n  = n0 + wid * 16 + il;
  const int mbase = mc * MCH;

  __shared__ __align__(16) __hip_bfloat16 lds[2][64 * 64];

  const float f1v = f1[hd * NROW + n];
  const float E1  = __builtin_amdgcn_exp2f(f1v);
  const float D1  = __builtin_amdgcn_exp2f(0.2f * f1v);
  const float iE1 = __builtin_amdgcn_exp2f(-f1v);

  const float* E2p = E2g + hd * NROW + mbase;
  const float* D2p = D2g + hd * NROW + mbase;
  const unsigned int* mwp = mw + (size_t)(mc * (MCH / 32)) * NROW + n;

  // staging: thread -> row o = tid>>2, quarter q = tid&3 (two 16B units)
  const int so = tid >> 2, sq = tid & 3;
  const __hip_bfloat16* hsrc = hTg + (hd * FOUT + so) * NROW + mbase + sq * 16;
  const int w0off = so * 64 + ((2 * sq)     ^ (so & 7)) * 8;
  const int w1off = so * 64 + ((2 * sq + 1) ^ (so & 7)) * 8;

  f32x4 acc[5];
#pragma unroll
  for (int c = 0; c < 5; ++c) { f32x4 z = {0.f,0.f,0.f,0.f}; acc[c] = z; }

  bf16x8 ones;
#pragma unroll
  for (int e = 0; e < 8; ++e) ones[e] = (__bf16)1.0f;

  {
    bf16x8 s0 = *(const bf16x8*)(hsrc);
    bf16x8 s1 = *(const bf16x8*)(hsrc + 8);
    *(bf16x8*)(&lds[0][w0off]) = s0;
    *(bf16x8*)(&lds[0][w1off]) = s1;
  }
  __syncthreads();

  for (int it = 0; it < ITERS; ++it) {
    const int cur = it & 1;
    bf16x8 s0n, s1n;
    const bool more = (it + 1 < ITERS);
    if (more) {                        // T14: issue next-tile loads early
      s0n = *(const bf16x8*)(hsrc + (it + 1) * 64);
      s1n = *(const bf16x8*)(hsrc + (it + 1) * 64 + 8);
    }

#pragma unroll
    for (int ks = 0; ks < 2; ++ks) {
      unsigned int mvs = mwp[(it * 2 + ks) * NROW] >> (kg * 8);
      const int mof = it * 64 + ks * 32 + kg * 8;
      f32x4 e2l = *(const f32x4*)(E2p + mof);
      f32x4 e2h = *(const f32x4*)(E2p + mof + 4);
      f32x4 d2l = *(const f32x4*)(D2p + mof);
      f32x4 d2h = *(const f32x4*)(D2p + mof + 4);

      bf16x8 afr[4];
#pragma unroll
      for (int c = 0; c < 4; ++c) {
        const int row = c * 16 + il;
        afr[c] = *(const bf16x8*)(
            &lds[cur][row * 64 + ((ks * 4 + kg) ^ (il & 7)) * 8]);
      }

      float p[8];
#pragma unroll
      for (int e = 0; e < 8; ++e) {
        float E2v = (e < 4) ? e2l[e] : e2h[e - 4];
        float D2v = (e < 4) ? d2l[e] : d2h[e - 4];
        bool neg = E2v < iE1;                       // s < 0
        float c2 = neg ? D2v : E2v;
        float c1 = neg ? D1 : E1;
        float q = c1 * c2;
        int msk = ((int)(mvs << (31 - e))) >> 31;   // bit e -> 0 / -1
        p[e] = __uint_as_float(__float_as_uint(q) & (unsigned)msk);
      }
      bf16x8 pb;
#pragma unroll
      for (int e = 0; e < 8; ++e) pb[e] = (__bf16)p[e];

#pragma unroll
      for (int c = 0; c < 4; ++c)
        acc[c] = __builtin_amdgcn_mfma_f32_16x16x32_bf16(afr[c], pb, acc[c], 0, 0, 0);
      acc[4] = __builtin_amdgcn_mfma_f32_16x16x32_bf16(ones, pb, acc[4], 0, 0, 0);
    }

    if (more) {
      *(bf16x8*)(&lds[cur ^ 1][w0off]) = s0n;
      *(bf16x8*)(&lds[cur ^ 1][w1off]) = s1n;
      __syncthreads();
    }
  }

  float* pp = part + ((size_t)((mc * NHEAD + hd) * NROW + n)) * 68;
#pragma unroll
  for (int c = 0; c < 4; ++c)
    *(f32x4*)(pp + c * 16 + kg * 4) = acc[c];
  if (kg == 0) pp[64] = acc[4][0];
}

// ---------------------------------------------------------------------------
// K4: combine S partial slices, divide, sigmoid, write out.
// ---------------------------------------------------------------------------
__global__ __launch_bounds__(256) void gat_comb(
    const float* __restrict__ part, float* __restrict__ out, int S)
{
  int flat = blockIdx.x * 256 + threadIdx.x;
  int n = flat >> 6, c4 = flat & 63;
  int hd = c4 >> 4, o4 = (c4 & 15) * 4;
  f32x4 num = {0.f,0.f,0.f,0.f};
  float L = 0.f;
  for (int s = 0; s < S; ++s) {
    const float* pp = part + ((size_t)((s * NHEAD + hd) * NROW + n)) * 68;
    f32x4 v = *(const f32x4*)(pp + o4);
    num += v;
    L += pp[64];
  }
  float invL = 1.0f / L;
  f32x4 r;
#pragma unroll
  for (int j = 0; j < 4; ++j)
    r[j] = 1.0f / (1.0f + __builtin_amdgcn_exp2f(-num[j] * invL * LOG2E));
  *(f32x4*)(out + (size_t)n * (NHEAD * FOUT) + hd * FOUT + o4) = r;
}

extern "C" void kernel_launch(void* const* d_in, const int* in_sizes, int n_in,
                              void* d_out, int out_size, void* d_ws, size_t ws_size,
                              hipStream_t stream) {
  const float* x   = (const float*)d_in[0];
  const int*   adj = (const int*)d_in[1];
  const float* W   = (const float*)d_in[2];
  const float* a1  = (const float*)d_in[3];
  const float* a2  = (const float*)d_in[4];
  float* out = (float*)d_out;

  char* ws = (char*)d_ws;
  const size_t WT_OFF = 0;
  const size_t HT_OFF = WT_OFF + (size_t)NHEAD * FOUT * FIN * 2;     // 256 KB
  const size_t F1_OFF = HT_OFF + (size_t)NHEAD * FOUT * NROW * 2;    // 4 MB
  const size_t E2_OFF = F1_OFF + (size_t)NHEAD * NROW * 4;
  const size_t D2_OFF = E2_OFF + (size_t)NHEAD * NROW * 4;
  const size_t MW_OFF = D2_OFF + (size_t)NHEAD * NROW * 4;
  const size_t PT_OFF = MW_OFF + (size_t)(NROW / 32) * NROW * 4;     // +8 MB
  const size_t PART_SLICE = (size_t)NHEAD * NROW * 68 * 4;           // 8.9 MB

  int S = (ws_size >= PT_OFF + 4 * PART_SLICE) ? 4
        : (ws_size >= PT_OFF + 2 * PART_SLICE) ? 2 : 1;

  __hip_bfloat16* WT = (__hip_bfloat16*)(ws + WT_OFF);
  __hip_bfloat16* hT = (__hip_bfloat16*)(ws + HT_OFF);
  float* f1 = (float*)(ws + F1_OFF);
  float* E2 = (float*)(ws + E2_OFF);
  float* D2 = (float*)(ws + D2_OFF);
  unsigned int* mw = (unsigned int*)(ws + MW_OFF);
  float* part = (float*)(ws + PT_OFF);

  wt_build<<<8, 256, 0, stream>>>(W, WT);
  gat_proj<<<NROW / 16, 256, 0, stream>>>(x, WT, a1, a2, hT, f1, E2, D2);
  mask_build<<<NROW / 4, 256, 0, stream>>>(adj, mw);
  if (S == 4)
    gat_attn<4><<<4 * NHEAD * 128, 256, 0, stream>>>(mw, hT, f1, E2, D2, part);
  else if (S == 2)
    gat_attn<2><<<2 * NHEAD * 128, 256, 0, stream>>>(mw, hT, f1, E2, D2, part);
  else
    gat_attn<1><<<1 * NHEAD * 128, 256, 0, stream>>>(mw, hT, f1, E2, D2, part);
  gat_comb<<<NROW * NHEAD * FOUT / 4 / 256, 256, 0, stream>>>(part, out, S);
}

// Round 4
// 273.206 us; speedup vs baseline: 1.0017x; 1.0017x over previous
//
#include <hip/hip_runtime.h>
#include <hip/hip_bf16.h>

#define NROW 8192
#define FIN  512
#define FOUT 64
#define NHEAD 4

constexpr float LOG2E = 1.44269504088896f;

typedef float f32x4 __attribute__((ext_vector_type(4)));
typedef __bf16 bf16x8 __attribute__((ext_vector_type(8)));

// ---------------------------------------------------------------------------
// K0: WT[hd][o][f] = bf16(W[hd][f][o])
// ---------------------------------------------------------------------------
__global__ __launch_bounds__(256) void wt_build(
    const float* __restrict__ W, __hip_bfloat16* __restrict__ WT)
{
  int t = blockIdx.x * 256 + threadIdx.x;       // 2048 threads = 4 heads x 512 f
  int hd = t >> 9, f = t & 511;
  const float* wp = W + (hd * FIN + f) * FOUT;
#pragma unroll 8
  for (int o = 0; o < FOUT; ++o)
    WT[(hd * FOUT + o) * FIN + f] = __float2bfloat16(wp[o]);
}

// ---------------------------------------------------------------------------
// K1 (fused): blocks [0, 2048): pack adj rows into bitmasks mw[w][n].
//             blocks [2048, 2560): h = x*W via MFMA -> hT, f1, E2, D2.
// The two halves are independent -> they run concurrently instead of as two
// serialized kernels.
// ---------------------------------------------------------------------------
__global__ __launch_bounds__(256) void gat_prep(
    const int* __restrict__ adj, unsigned int* __restrict__ mw,
    const float* __restrict__ x, const __hip_bfloat16* __restrict__ WT,
    const float* __restrict__ a1, const float* __restrict__ a2,
    __hip_bfloat16* __restrict__ hT, float* __restrict__ f1,
    float* __restrict__ E2, float* __restrict__ D2)
{
  const int tid = threadIdx.x;
  if (blockIdx.x < NROW / 4) {
    // ---- mask pack: 4 rows per block, wave per row
    const int wid = tid >> 6, lane = tid & 63;
    const int nrow = blockIdx.x * 4 + wid;
    const int* ap = adj + (size_t)nrow * NROW;
#pragma unroll 4
    for (int it = 0; it < NROW / 64; ++it) {
      unsigned long long b = __ballot(ap[it * 64 + lane] != 0);
      if (lane == 0) {
        mw[(it * 2) * NROW + nrow]     = (unsigned int)b;
        mw[(it * 2 + 1) * NROW + nrow] = (unsigned int)(b >> 32);
      }
    }
    return;
  }

  // ---- projection: wave = head, block covers 16 rows
  const int bp = blockIdx.x - NROW / 4;
  const int hd = tid >> 6, lane = tid & 63;
  const int il = lane & 15, kg = lane >> 4;
  const int n0 = bp * 16;
  const __hip_bfloat16* wtp = WT + hd * (FOUT * FIN);
  const float* xp = x + (n0 + il) * FIN + kg * 8;

  f32x4 acc[4];
#pragma unroll
  for (int c = 0; c < 4; ++c) { f32x4 z = {0.f,0.f,0.f,0.f}; acc[c] = z; }

#pragma unroll 2
  for (int kk = 0; kk < FIN / 32; ++kk) {
    bf16x8 af[4];
#pragma unroll
    for (int c = 0; c < 4; ++c)
      af[c] = *(const bf16x8*)(wtp + (c * 16 + il) * FIN + kk * 32 + kg * 8);
    f32x4 xl = *(const f32x4*)(xp + kk * 32);
    f32x4 xh = *(const f32x4*)(xp + kk * 32 + 4);
    bf16x8 xb;
#pragma unroll
    for (int e = 0; e < 4; ++e) {
      xb[e]     = (__bf16)xl[e];
      xb[4 + e] = (__bf16)xh[e];
    }
#pragma unroll
    for (int c = 0; c < 4; ++c)
      acc[c] = __builtin_amdgcn_mfma_f32_16x16x32_bf16(af[c], xb, acc[c], 0, 0, 0);
  }

  const int n = n0 + il;
  float p1 = 0.f, p2 = 0.f;
#pragma unroll
  for (int c = 0; c < 4; ++c) {
    f32x4 a1v = *(const f32x4*)(a1 + hd * FOUT + c * 16 + kg * 4);
    f32x4 a2v = *(const f32x4*)(a2 + hd * FOUT + c * 16 + kg * 4);
#pragma unroll
    for (int r = 0; r < 4; ++r) {
      float hv = acc[c][r];
      hT[(hd * FOUT + c * 16 + kg * 4 + r) * NROW + n] = __float2bfloat16(hv);
      p1 = fmaf(hv, a1v[r], p1);
      p2 = fmaf(hv, a2v[r], p2);
    }
  }
  p1 += __shfl_xor(p1, 16); p1 += __shfl_xor(p1, 32);
  p2 += __shfl_xor(p2, 16); p2 += __shfl_xor(p2, 32);
  if (kg == 0) {
    float f1c = p1 * LOG2E;
    float f2c = p2 * LOG2E;
    f1[hd * NROW + n] = f1c;
    E2[hd * NROW + n] = __builtin_amdgcn_exp2f(f2c);
    D2[hd * NROW + n] = __builtin_amdgcn_exp2f(0.2f * f2c);
  }
}

// ---------------------------------------------------------------------------
// K3: attention partials. All inner-loop operands are LDS- or reg-resident:
//   - E2/D2 tables for the whole m-chunk staged to LDS once per block
//   - mask words pre-loaded into registers per 8-iteration segment
//   - hT tile [64o][64m] XOR-swizzled LDS, double-buffered, reg-prefetched
// Block = 4 waves, same head, 64 rows. 1 barrier/iter.
// ---------------------------------------------------------------------------
template <int S>
__global__ __launch_bounds__(256, 4) void gat_attn(
    const unsigned int* __restrict__ mw, const __hip_bfloat16* __restrict__ hTg,
    const float* __restrict__ f1, const float* __restrict__ E2g,
    const float* __restrict__ D2g, float* __restrict__ part)
{
  constexpr int MCH = NROW / S;
  constexpr int NSEG = MCH / 64 / 8;          // 8 iters per segment
  const int tid = threadIdx.x;
  const int wid = tid >> 6, lane = tid & 63;
  const int il = lane & 15, kg = lane >> 4;

  // XCD-chunked block swizzle (grid % 8 == 0)
  const int nwg = S * NHEAD * 128;
  const int bid = (blockIdx.x & 7) * (nwg >> 3) + (blockIdx.x >> 3);
  const int rg = bid & 127;
  const int hd = (bid >> 7) & 3;
  const int mc = bid >> 9;
  const int n0 = rg * 64;
  const int n  = n0 + wid * 16 + il;
  const int mbase = mc * MCH;

  __shared__ __align__(16) __hip_bfloat16 lds[2][64 * 64];   // 16 KB
  __shared__ __align__(16) float lds_e[MCH];                 // 8 KB (S=4)
  __shared__ __align__(16) float lds_d[MCH];                 // 8 KB

  const float f1v = f1[hd * NROW + n];
  const float E1  = __builtin_amdgcn_exp2f(f1v);
  const float D1  = __builtin_amdgcn_exp2f(0.2f * f1v);
  const float iE1 = __builtin_amdgcn_exp2f(-f1v);

  const float* E2p = E2g + hd * NROW + mbase;
  const float* D2p = D2g + hd * NROW + mbase;
  const unsigned int* mwp = mw + (size_t)(mc * (MCH / 32)) * NROW + n;

  // staging map: thread -> row o = tid>>2, quarter q = tid&3 (two 16B units)
  const int so = tid >> 2, sq = tid & 3;
  const __hip_bfloat16* hs = hTg + (hd * FOUT + so) * NROW + mbase + sq * 16;
  const int w0off = so * 64 + ((2 * sq)     ^ (so & 7)) * 8;
  const int w1off = so * 64 + ((2 * sq + 1) ^ (so & 7)) * 8;

  f32x4 acc[5];
#pragma unroll
  for (int c = 0; c < 5; ++c) { f32x4 z = {0.f,0.f,0.f,0.f}; acc[c] = z; }

  bf16x8 ones;
#pragma unroll
  for (int e = 0; e < 8; ++e) ones[e] = (__bf16)1.0f;

  // stage tables + tile 0
#pragma unroll
  for (int q = 0; q < MCH / 1024; ++q) {
    int idx = (q * 256 + tid) * 4;
    *(f32x4*)(&lds_e[idx]) = *(const f32x4*)(E2p + idx);
    *(f32x4*)(&lds_d[idx]) = *(const f32x4*)(D2p + idx);
  }
  {
    bf16x8 s0 = *(const bf16x8*)(hs);
    bf16x8 s1 = *(const bf16x8*)(hs + 8);
    *(bf16x8*)(&lds[0][w0off]) = s0;
    *(bf16x8*)(&lds[0][w1off]) = s1;
  }
  __syncthreads();

  int tb = 0;                                 // table base (f32 elems)
  for (int seg = 0; seg < NSEG; ++seg) {
    // mask words for this segment: 16 coalesced loads, one latency exposure
    unsigned int mreg[16];
#pragma unroll
    for (int j = 0; j < 16; ++j) mreg[j] = mwp[j * NROW];
    mwp += 16 * (size_t)NROW;

#pragma unroll
    for (int it2 = 0; it2 < 8; ++it2) {
      const int cur = (seg * 8 + it2) & 1;
      const bool more = (seg < NSEG - 1) || (it2 < 7);
      bf16x8 s0n, s1n;
      if (more) {                             // T14: issue next-tile loads early
        s0n = *(const bf16x8*)(hs + 64);
        s1n = *(const bf16x8*)(hs + 64 + 8);
      }

#pragma unroll
      for (int ks = 0; ks < 2; ++ks) {
        unsigned int mvs = mreg[it2 * 2 + ks] >> (kg * 8);
        const int mof = tb + it2 * 64 + ks * 32 + kg * 8;
        f32x4 e2l = *(const f32x4*)(&lds_e[mof]);
        f32x4 e2h = *(const f32x4*)(&lds_e[mof + 4]);
        f32x4 d2l = *(const f32x4*)(&lds_d[mof]);
        f32x4 d2h = *(const f32x4*)(&lds_d[mof + 4]);

        bf16x8 afr[4];
#pragma unroll
        for (int c = 0; c < 4; ++c) {
          const int row = c * 16 + il;
          afr[c] = *(const bf16x8*)(
              &lds[cur][row * 64 + ((ks * 4 + kg) ^ (il & 7)) * 8]);
        }

        float p[8];
#pragma unroll
        for (int e = 0; e < 8; ++e) {
          float E2v = (e < 4) ? e2l[e] : e2h[e - 4];
          float D2v = (e < 4) ? d2l[e] : d2h[e - 4];
          bool neg = E2v < iE1;                       // s < 0
          float c2 = neg ? D2v : E2v;
          float c1 = neg ? D1 : E1;
          float q = c1 * c2;
          int msk = ((int)(mvs << (31 - e))) >> 31;   // bit e -> 0 / -1
          p[e] = __uint_as_float(__float_as_uint(q) & (unsigned)msk);
        }
        bf16x8 pb;
#pragma unroll
        for (int e = 0; e < 8; ++e) pb[e] = (__bf16)p[e];

#pragma unroll
        for (int c = 0; c < 4; ++c)
          acc[c] = __builtin_amdgcn_mfma_f32_16x16x32_bf16(afr[c], pb, acc[c], 0, 0, 0);
        acc[4] = __builtin_amdgcn_mfma_f32_16x16x32_bf16(ones, pb, acc[4], 0, 0, 0);
      }

      if (more) {
        *(bf16x8*)(&lds[cur ^ 1][w0off]) = s0n;
        *(bf16x8*)(&lds[cur ^ 1][w1off]) = s1n;
        __syncthreads();
      }
      hs += 64;
    }
    tb += 512;
  }

  float* pp = part + ((size_t)((mc * NHEAD + hd) * NROW + n)) * 68;
#pragma unroll
  for (int c = 0; c < 4; ++c)
    *(f32x4*)(pp + c * 16 + kg * 4) = acc[c];
  if (kg == 0) pp[64] = acc[4][0];
}

// ---------------------------------------------------------------------------
// K4: combine S partial slices, divide, sigmoid, write out.
// ---------------------------------------------------------------------------
__global__ __launch_bounds__(256) void gat_comb(
    const float* __restrict__ part, float* __restrict__ out, int S)
{
  int flat = blockIdx.x * 256 + threadIdx.x;
  int n = flat >> 6, c4 = flat & 63;
  int hd = c4 >> 4, o4 = (c4 & 15) * 4;
  f32x4 num = {0.f,0.f,0.f,0.f};
  float L = 0.f;
  for (int s = 0; s < S; ++s) {
    const float* pp = part + ((size_t)((s * NHEAD + hd) * NROW + n)) * 68;
    f32x4 v = *(const f32x4*)(pp + o4);
    num += v;
    L += pp[64];
  }
  float invL = 1.0f / L;
  f32x4 r;
#pragma unroll
  for (int j = 0; j < 4; ++j)
    r[j] = 1.0f / (1.0f + __builtin_amdgcn_exp2f(-num[j] * invL * LOG2E));
  *(f32x4*)(out + (size_t)n * (NHEAD * FOUT) + hd * FOUT + o4) = r;
}

extern "C" void kernel_launch(void* const* d_in, const int* in_sizes, int n_in,
                              void* d_out, int out_size, void* d_ws, size_t ws_size,
                              hipStream_t stream) {
  const float* x   = (const float*)d_in[0];
  const int*   adj = (const int*)d_in[1];
  const float* W   = (const float*)d_in[2];
  const float* a1  = (const float*)d_in[3];
  const float* a2  = (const float*)d_in[4];
  float* out = (float*)d_out;

  char* ws = (char*)d_ws;
  const size_t WT_OFF = 0;
  const size_t HT_OFF = WT_OFF + (size_t)NHEAD * FOUT * FIN * 2;     // 256 KB
  const size_t F1_OFF = HT_OFF + (size_t)NHEAD * FOUT * NROW * 2;    // 4 MB
  const size_t E2_OFF = F1_OFF + (size_t)NHEAD * NROW * 4;
  const size_t D2_OFF = E2_OFF + (size_t)NHEAD * NROW * 4;
  const size_t MW_OFF = D2_OFF + (size_t)NHEAD * NROW * 4;
  const size_t PT_OFF = MW_OFF + (size_t)(NROW / 32) * NROW * 4;     // +8 MB
  const size_t PART_SLICE = (size_t)NHEAD * NROW * 68 * 4;           // 8.9 MB

  int S = (ws_size >= PT_OFF + 4 * PART_SLICE) ? 4
        : (ws_size >= PT_OFF + 2 * PART_SLICE) ? 2 : 1;

  __hip_bfloat16* WT = (__hip_bfloat16*)(ws + WT_OFF);
  __hip_bfloat16* hT = (__hip_bfloat16*)(ws + HT_OFF);
  float* f1 = (float*)(ws + F1_OFF);
  float* E2 = (float*)(ws + E2_OFF);
  float* D2 = (float*)(ws + D2_OFF);
  unsigned int* mw = (unsigned int*)(ws + MW_OFF);
  float* part = (float*)(ws + PT_OFF);

  wt_build<<<8, 256, 0, stream>>>(W, WT);
  gat_prep<<<NROW / 4 + NROW / 16, 256, 0, stream>>>(
      adj, mw, x, WT, a1, a2, hT, f1, E2, D2);
  if (S == 4)
    gat_attn<4><<<4 * NHEAD * 128, 256, 0, stream>>>(mw, hT, f1, E2, D2, part);
  else if (S == 2)
    gat_attn<2><<<2 * NHEAD * 128, 256, 0, stream>>>(mw, hT, f1, E2, D2, part);
  else
    gat_attn<1><<<1 * NHEAD * 128, 256, 0, stream>>>(mw, hT, f1, E2, D2, part);
  gat_comb<<<NROW * NHEAD * FOUT / 4 / 256, 256, 0, stream>>>(part, out, S);
}

// Round 5
// 195.070 us; speedup vs baseline: 1.4029x; 1.4006x over previous
//
#include <hip/hip_runtime.h>
#include <hip/hip_bf16.h>

#define NROW 8192
#define FIN  512
#define FOUT 64
#define NHEAD 4

constexpr float LOG2E = 1.44269504088896f;

typedef float f32x4 __attribute__((ext_vector_type(4)));
typedef int   i32x4 __attribute__((ext_vector_type(4)));
typedef __bf16 bf16x8 __attribute__((ext_vector_type(8)));

// ---------------------------------------------------------------------------
// K0: WT[hd][o][f] = bf16(W[hd][f][o])
// ---------------------------------------------------------------------------
__global__ __launch_bounds__(256) void wt_build(
    const float* __restrict__ W, __hip_bfloat16* __restrict__ WT)
{
  int t = blockIdx.x * 256 + threadIdx.x;       // 2048 threads = 4 heads x 512 f
  int hd = t >> 9, f = t & 511;
  const float* wp = W + (hd * FIN + f) * FOUT;
#pragma unroll 8
  for (int o = 0; o < FOUT; ++o)
    WT[(hd * FOUT + o) * FIN + f] = __float2bfloat16(wp[o]);
}

// ---------------------------------------------------------------------------
// K1: h = x*W via MFMA. Wave = head; block covers 16 rows.
// Emits hT (bf16 [hd][o][n]), f1c=(h.a1)*LOG2E, E2=exp2(f2c), D2=exp2(.2*f2c)
// ---------------------------------------------------------------------------
__global__ __launch_bounds__(256) void gat_proj(
    const float* __restrict__ x, const __hip_bfloat16* __restrict__ WT,
    const float* __restrict__ a1, const float* __restrict__ a2,
    __hip_bfloat16* __restrict__ hT, float* __restrict__ f1,
    float* __restrict__ E2, float* __restrict__ D2)
{
  const int tid = threadIdx.x;
  const int hd = tid >> 6, lane = tid & 63;
  const int il = lane & 15, kg = lane >> 4;
  const int n0 = blockIdx.x * 16;
  const __hip_bfloat16* wtp = WT + hd * (FOUT * FIN);
  const float* xp = x + (n0 + il) * FIN + kg * 8;

  f32x4 acc[4];
#pragma unroll
  for (int c = 0; c < 4; ++c) { f32x4 z = {0.f,0.f,0.f,0.f}; acc[c] = z; }

#pragma unroll 2
  for (int kk = 0; kk < FIN / 32; ++kk) {
    bf16x8 af[4];
#pragma unroll
    for (int c = 0; c < 4; ++c)
      af[c] = *(const bf16x8*)(wtp + (c * 16 + il) * FIN + kk * 32 + kg * 8);
    f32x4 xl = *(const f32x4*)(xp + kk * 32);
    f32x4 xh = *(const f32x4*)(xp + kk * 32 + 4);
    bf16x8 xb;
#pragma unroll
    for (int e = 0; e < 4; ++e) {
      xb[e]     = (__bf16)xl[e];
      xb[4 + e] = (__bf16)xh[e];
    }
#pragma unroll
    for (int c = 0; c < 4; ++c)
      acc[c] = __builtin_amdgcn_mfma_f32_16x16x32_bf16(af[c], xb, acc[c], 0, 0, 0);
  }

  const int n = n0 + il;
  float p1 = 0.f, p2 = 0.f;
#pragma unroll
  for (int c = 0; c < 4; ++c) {
    f32x4 a1v = *(const f32x4*)(a1 + hd * FOUT + c * 16 + kg * 4);
    f32x4 a2v = *(const f32x4*)(a2 + hd * FOUT + c * 16 + kg * 4);
#pragma unroll
    for (int r = 0; r < 4; ++r) {
      float hv = acc[c][r];
      hT[(hd * FOUT + c * 16 + kg * 4 + r) * NROW + n] = __float2bfloat16(hv);
      p1 = fmaf(hv, a1v[r], p1);
      p2 = fmaf(hv, a2v[r], p2);
    }
  }
  p1 += __shfl_xor(p1, 16); p1 += __shfl_xor(p1, 32);
  p2 += __shfl_xor(p2, 16); p2 += __shfl_xor(p2, 32);
  if (kg == 0) {
    float f1c = p1 * LOG2E;
    float f2c = p2 * LOG2E;
    f1[hd * NROW + n] = f1c;
    E2[hd * NROW + n] = __builtin_amdgcn_exp2f(f2c);
    D2[hd * NROW + n] = __builtin_amdgcn_exp2f(0.2f * f2c);
  }
}

// ---------------------------------------------------------------------------
// K2: adj -> bitmasks, streaming-optimized.
// Wave = 1 row. Per 2048-col chunk: each lane loads 8 int4 (1KB/wave-instr,
// coalesced), builds a u32 of 8 nibbles (nibble j = nonzero bits of its 4
// cols), then ds_bpermute transposes nibbles so each lane assembles its OWN
// 32-bit word (cols 32w..32w+31) and stores it. No ballots, no barriers.
//   col of (chunk c, instr j, lane l, comp b) = c*2048 + 4*(j*64+l) + b
//   word w (bit 4t+b) <- lane 8*(w&7)+t, nibble j=w>>3, comp b
// ---------------------------------------------------------------------------
__global__ __launch_bounds__(256) void mask_build(
    const int* __restrict__ adj, unsigned int* __restrict__ mw)
{
  const int tid = threadIdx.x;
  const int wid = tid >> 6, lane = tid & 63;
  const int row = blockIdx.x * 4 + wid;
  const i32x4* ap = (const i32x4*)(adj + (size_t)row * NROW);
  const int bpbase = (lane & 7) << 5;      // byte index of lane 8*(l&7)
  const int sh = (lane >> 3) << 2;         // nibble select for this lane

#pragma unroll
  for (int c = 0; c < 4; ++c) {
    i32x4 v[8];
#pragma unroll
    for (int j = 0; j < 8; ++j) v[j] = ap[c * 512 + j * 64 + lane];

    unsigned nibs = 0;
#pragma unroll
    for (int j = 0; j < 8; ++j) {
      unsigned b0 = min((unsigned)v[j][0], 1u);
      unsigned b1 = min((unsigned)v[j][1], 1u);
      unsigned b2 = min((unsigned)v[j][2], 1u);
      unsigned b3 = min((unsigned)v[j][3], 1u);
      unsigned nib = b0 | (b1 << 1) | (b2 << 2) | (b3 << 3);
      nibs |= nib << (4 * j);
    }

    unsigned w = 0;
#pragma unroll
    for (int t = 0; t < 8; ++t) {
      unsigned bp = (unsigned)__builtin_amdgcn_ds_bpermute(bpbase + 4 * t,
                                                           (int)nibs);
      w |= ((bp >> sh) & 0xFu) << (4 * t);
    }
    mw[(size_t)(c * 64 + lane) * NROW + row] = w;
  }
}

// ---------------------------------------------------------------------------
// K3: attention partials. All inner-loop operands LDS/reg-resident:
//   E2/D2 chunk tables in LDS; mask words in registers per 8-iter segment;
//   hT tile [64o][64m] XOR-swizzled LDS, double-buffered, reg-prefetched.
// Block = 4 waves, same head, 64 rows. 1 barrier/iter.
// ---------------------------------------------------------------------------
template <int S>
__global__ __launch_bounds__(256, 4) void gat_attn(
    const unsigned int* __restrict__ mw, const __hip_bfloat16* __restrict__ hTg,
    const float* __restrict__ f1, const float* __restrict__ E2g,
    const float* __restrict__ D2g, float* __restrict__ part)
{
  constexpr int MCH = NROW / S;
  constexpr int NSEG = MCH / 64 / 8;
  const int tid = threadIdx.x;
  const int wid = tid >> 6, lane = tid & 63;
  const int il = lane & 15, kg = lane >> 4;

  const int nwg = S * NHEAD * 128;
  const int bid = (blockIdx.x & 7) * (nwg >> 3) + (blockIdx.x >> 3);
  const int rg = bid & 127;
  const int hd = (bid >> 7) & 3;
  const int mc = bid >> 9;
  const int n0 = rg * 64;
  const int n  = n0 + wid * 16 + il;
  const int mbase = mc * MCH;

  __shared__ __align__(16) __hip_bfloat16 lds[2][64 * 64];
  __shared__ __align__(16) float lds_e[MCH];
  __shared__ __align__(16) float lds_d[MCH];

  const float f1v = f1[hd * NROW + n];
  const float E1  = __builtin_amdgcn_exp2f(f1v);
  const float D1  = __builtin_amdgcn_exp2f(0.2f * f1v);
  const float iE1 = __builtin_amdgcn_exp2f(-f1v);

  const float* E2p = E2g + hd * NROW + mbase;
  const float* D2p = D2g + hd * NROW + mbase;
  const unsigned int* mwp = mw + (size_t)(mc * (MCH / 32)) * NROW + n;

  const int so = tid >> 2, sq = tid & 3;
  const __hip_bfloat16* hs = hTg + (hd * FOUT + so) * NROW + mbase + sq * 16;
  const int w0off = so * 64 + ((2 * sq)     ^ (so & 7)) * 8;
  const int w1off = so * 64 + ((2 * sq + 1) ^ (so & 7)) * 8;

  f32x4 acc[5];
#pragma unroll
  for (int c = 0; c < 5; ++c) { f32x4 z = {0.f,0.f,0.f,0.f}; acc[c] = z; }

  bf16x8 ones;
#pragma unroll
  for (int e = 0; e < 8; ++e) ones[e] = (__bf16)1.0f;

#pragma unroll
  for (int q = 0; q < MCH / 1024; ++q) {
    int idx = (q * 256 + tid) * 4;
    *(f32x4*)(&lds_e[idx]) = *(const f32x4*)(E2p + idx);
    *(f32x4*)(&lds_d[idx]) = *(const f32x4*)(D2p + idx);
  }
  {
    bf16x8 s0 = *(const bf16x8*)(hs);
    bf16x8 s1 = *(const bf16x8*)(hs + 8);
    *(bf16x8*)(&lds[0][w0off]) = s0;
    *(bf16x8*)(&lds[0][w1off]) = s1;
  }
  __syncthreads();

  int tb = 0;
  for (int seg = 0; seg < NSEG; ++seg) {
    unsigned int mreg[16];
#pragma unroll
    for (int j = 0; j < 16; ++j) mreg[j] = mwp[j * NROW];
    mwp += 16 * (size_t)NROW;

#pragma unroll
    for (int it2 = 0; it2 < 8; ++it2) {
      const int cur = (seg * 8 + it2) & 1;
      const bool more = (seg < NSEG - 1) || (it2 < 7);
      bf16x8 s0n, s1n;
      if (more) {                             // T14: issue next-tile loads early
        s0n = *(const bf16x8*)(hs + 64);
        s1n = *(const bf16x8*)(hs + 64 + 8);
      }

#pragma unroll
      for (int ks = 0; ks < 2; ++ks) {
        unsigned int mvs = mreg[it2 * 2 + ks] >> (kg * 8);
        const int mof = tb + it2 * 64 + ks * 32 + kg * 8;
        f32x4 e2l = *(const f32x4*)(&lds_e[mof]);
        f32x4 e2h = *(const f32x4*)(&lds_e[mof + 4]);
        f32x4 d2l = *(const f32x4*)(&lds_d[mof]);
        f32x4 d2h = *(const f32x4*)(&lds_d[mof + 4]);

        bf16x8 afr[4];
#pragma unroll
        for (int c = 0; c < 4; ++c) {
          const int row = c * 16 + il;
          afr[c] = *(const bf16x8*)(
              &lds[cur][row * 64 + ((ks * 4 + kg) ^ (il & 7)) * 8]);
        }

        float p[8];
#pragma unroll
        for (int e = 0; e < 8; ++e) {
          float E2v = (e < 4) ? e2l[e] : e2h[e - 4];
          float D2v = (e < 4) ? d2l[e] : d2h[e - 4];
          bool neg = E2v < iE1;                       // s < 0
          float c2 = neg ? D2v : E2v;
          float c1 = neg ? D1 : E1;
          float q = c1 * c2;
          int msk = ((int)(mvs << (31 - e))) >> 31;   // bit e -> 0 / -1
          p[e] = __uint_as_float(__float_as_uint(q) & (unsigned)msk);
        }
        bf16x8 pb;
#pragma unroll
        for (int e = 0; e < 8; ++e) pb[e] = (__bf16)p[e];

#pragma unroll
        for (int c = 0; c < 4; ++c)
          acc[c] = __builtin_amdgcn_mfma_f32_16x16x32_bf16(afr[c], pb, acc[c], 0, 0, 0);
        acc[4] = __builtin_amdgcn_mfma_f32_16x16x32_bf16(ones, pb, acc[4], 0, 0, 0);
      }

      if (more) {
        *(bf16x8*)(&lds[cur ^ 1][w0off]) = s0n;
        *(bf16x8*)(&lds[cur ^ 1][w1off]) = s1n;
        __syncthreads();
      }
      hs += 64;
    }
    tb += 512;
  }

  float* pp = part + ((size_t)((mc * NHEAD + hd) * NROW + n)) * 68;
#pragma unroll
  for (int c = 0; c < 4; ++c)
    *(f32x4*)(pp + c * 16 + kg * 4) = acc[c];
  if (kg == 0) pp[64] = acc[4][0];
}

// ---------------------------------------------------------------------------
// K4: combine S partial slices, divide, sigmoid, write out.
// ---------------------------------------------------------------------------
__global__ __launch_bounds__(256) void gat_comb(
    const float* __restrict__ part, float* __restrict__ out, int S)
{
  int flat = blockIdx.x * 256 + threadIdx.x;
  int n = flat >> 6, c4 = flat & 63;
  int hd = c4 >> 4, o4 = (c4 & 15) * 4;
  f32x4 num = {0.f,0.f,0.f,0.f};
  float L = 0.f;
  for (int s = 0; s < S; ++s) {
    const float* pp = part + ((size_t)((s * NHEAD + hd) * NROW + n)) * 68;
    f32x4 v = *(const f32x4*)(pp + o4);
    num += v;
    L += pp[64];
  }
  float invL = 1.0f / L;
  f32x4 r;
#pragma unroll
  for (int j = 0; j < 4; ++j)
    r[j] = 1.0f / (1.0f + __builtin_amdgcn_exp2f(-num[j] * invL * LOG2E));
  *(f32x4*)(out + (size_t)n * (NHEAD * FOUT) + hd * FOUT + o4) = r;
}

extern "C" void kernel_launch(void* const* d_in, const int* in_sizes, int n_in,
                              void* d_out, int out_size, void* d_ws, size_t ws_size,
                              hipStream_t stream) {
  const float* x   = (const float*)d_in[0];
  const int*   adj = (const int*)d_in[1];
  const float* W   = (const float*)d_in[2];
  const float* a1  = (const float*)d_in[3];
  const float* a2  = (const float*)d_in[4];
  float* out = (float*)d_out;

  char* ws = (char*)d_ws;
  const size_t WT_OFF = 0;
  const size_t HT_OFF = WT_OFF + (size_t)NHEAD * FOUT * FIN * 2;     // 256 KB
  const size_t F1_OFF = HT_OFF + (size_t)NHEAD * FOUT * NROW * 2;    // 4 MB
  const size_t E2_OFF = F1_OFF + (size_t)NHEAD * NROW * 4;
  const size_t D2_OFF = E2_OFF + (size_t)NHEAD * NROW * 4;
  const size_t MW_OFF = D2_OFF + (size_t)NHEAD * NROW * 4;
  const size_t PT_OFF = MW_OFF + (size_t)(NROW / 32) * NROW * 4;     // +8 MB
  const size_t PART_SLICE = (size_t)NHEAD * NROW * 68 * 4;           // 8.9 MB

  int S = (ws_size >= PT_OFF + 4 * PART_SLICE) ? 4
        : (ws_size >= PT_OFF + 2 * PART_SLICE) ? 2 : 1;

  __hip_bfloat16* WT = (__hip_bfloat16*)(ws + WT_OFF);
  __hip_bfloat16* hT = (__hip_bfloat16*)(ws + HT_OFF);
  float* f1 = (float*)(ws + F1_OFF);
  float* E2 = (float*)(ws + E2_OFF);
  float* D2 = (float*)(ws + D2_OFF);
  unsigned int* mw = (unsigned int*)(ws + MW_OFF);
  float* part = (float*)(ws + PT_OFF);

  wt_build<<<8, 256, 0, stream>>>(W, WT);
  gat_proj<<<NROW / 16, 256, 0, stream>>>(x, WT, a1, a2, hT, f1, E2, D2);
  mask_build<<<NROW / 4, 256, 0, stream>>>(adj, mw);
  if (S == 4)
    gat_attn<4><<<4 * NHEAD * 128, 256, 0, stream>>>(mw, hT, f1, E2, D2, part);
  else if (S == 2)
    gat_attn<2><<<2 * NHEAD * 128, 256, 0, stream>>>(mw, hT, f1, E2, D2, part);
  else
    gat_attn<1><<<1 * NHEAD * 128, 256, 0, stream>>>(mw, hT, f1, E2, D2, part);
  gat_comb<<<NROW * NHEAD * FOUT / 4 / 256, 256, 0, stream>>>(part, out, S);
}

// Round 6
// 178.498 us; speedup vs baseline: 1.5332x; 1.0928x over previous
//
#include <hip/hip_runtime.h>
#include <hip/hip_bf16.h>

#define NROW 8192
#define FIN  512
#define FOUT 64
#define NHEAD 4

constexpr float LOG2E = 1.44269504088896f;

typedef float f32x4 __attribute__((ext_vector_type(4)));
typedef int   i32x4 __attribute__((ext_vector_type(4)));
typedef __bf16 bf16x8 __attribute__((ext_vector_type(8)));

// ---------------------------------------------------------------------------
// K0: WT[hd][o][f] = bf16(W[hd][f][o])
// ---------------------------------------------------------------------------
__global__ __launch_bounds__(256) void wt_build(
    const float* __restrict__ W, __hip_bfloat16* __restrict__ WT)
{
  int t = blockIdx.x * 256 + threadIdx.x;       // 2048 threads = 4 heads x 512 f
  int hd = t >> 9, f = t & 511;
  const float* wp = W + (hd * FIN + f) * FOUT;
#pragma unroll 8
  for (int o = 0; o < FOUT; ++o)
    WT[(hd * FOUT + o) * FIN + f] = __float2bfloat16(wp[o]);
}

// ---------------------------------------------------------------------------
// K1: h = x*W via MFMA. Block = one head, 4 waves, 64 n-rows.
// WT head staged once in XOR-swizzled LDS (ds_read_b128 in K-loop).
// Epilogue: f1/E2/D2 + hT via LDS transpose -> 128B-contiguous stores.
// ---------------------------------------------------------------------------
__global__ __launch_bounds__(256) void gat_proj(
    const float* __restrict__ x, const __hip_bfloat16* __restrict__ WT,
    const float* __restrict__ a1, const float* __restrict__ a2,
    __hip_bfloat16* __restrict__ hT, float* __restrict__ f1,
    float* __restrict__ E2, float* __restrict__ D2)
{
  const int tid = threadIdx.x;
  const int wid = tid >> 6, lane = tid & 63;
  const int il = lane & 15, kg = lane >> 4;
  const int hd = blockIdx.x & 3;
  const int rg = blockIdx.x >> 2;
  const int n0 = rg * 64;

  __shared__ __align__(16) __hip_bfloat16 wt_lds[64 * 512];   // 64 KB
  __shared__ __align__(16) __hip_bfloat16 ht_tile[64 * 66];   // 8.25 KB

  // stage this head's WT, swizzled: 16B unit u at row o goes to u ^ (o&7)
  {
    const int o = tid >> 2, q = tid & 3;
    const __hip_bfloat16* src = WT + (size_t)(hd * FOUT + o) * FIN;
#pragma unroll
    for (int k = 0; k < 16; ++k) {
      int u = q * 16 + k;
      bf16x8 vv = *(const bf16x8*)(src + u * 8);
      *(bf16x8*)(&wt_lds[o * 512 + (u ^ (o & 7)) * 8]) = vv;
    }
  }
  __syncthreads();

  const int n = n0 + wid * 16 + il;
  const float* xp = x + (size_t)n * FIN + kg * 8;

  f32x4 acc[4];
#pragma unroll
  for (int c = 0; c < 4; ++c) { f32x4 z = {0.f,0.f,0.f,0.f}; acc[c] = z; }

#pragma unroll 4
  for (int kk = 0; kk < FIN / 32; ++kk) {
    f32x4 xl = *(const f32x4*)(xp + kk * 32);
    f32x4 xh = *(const f32x4*)(xp + kk * 32 + 4);
    bf16x8 xb;
#pragma unroll
    for (int e = 0; e < 4; ++e) {
      xb[e]     = (__bf16)xl[e];
      xb[4 + e] = (__bf16)xh[e];
    }
#pragma unroll
    for (int c = 0; c < 4; ++c) {
      const int o = c * 16 + il;
      bf16x8 af = *(const bf16x8*)(
          &wt_lds[o * 512 + ((kk * 4 + kg) ^ (il & 7)) * 8]);
      acc[c] = __builtin_amdgcn_mfma_f32_16x16x32_bf16(af, xb, acc[c], 0, 0, 0);
    }
  }

  // f1 / E2 / D2 (reduce over o held in this lane, then over kg)
  float p1 = 0.f, p2 = 0.f;
#pragma unroll
  for (int c = 0; c < 4; ++c) {
    f32x4 a1v = *(const f32x4*)(a1 + hd * FOUT + c * 16 + kg * 4);
    f32x4 a2v = *(const f32x4*)(a2 + hd * FOUT + c * 16 + kg * 4);
#pragma unroll
    for (int r = 0; r < 4; ++r) {
      p1 = fmaf(acc[c][r], a1v[r], p1);
      p2 = fmaf(acc[c][r], a2v[r], p2);
    }
  }
  p1 += __shfl_xor(p1, 16); p1 += __shfl_xor(p1, 32);
  p2 += __shfl_xor(p2, 16); p2 += __shfl_xor(p2, 32);
  if (kg == 0) {
    float f1c = p1 * LOG2E;
    float f2c = p2 * LOG2E;
    f1[hd * NROW + n] = f1c;
    E2[hd * NROW + n] = __builtin_amdgcn_exp2f(f2c);
    D2[hd * NROW + n] = __builtin_amdgcn_exp2f(0.2f * f2c);
  }

  // hT: transpose through LDS, then coalesced 16B stores
#pragma unroll
  for (int c = 0; c < 4; ++c)
#pragma unroll
    for (int r = 0; r < 4; ++r)
      ht_tile[(c * 16 + kg * 4 + r) * 66 + wid * 16 + il] =
          __float2bfloat16(acc[c][r]);
  __syncthreads();
  {
    const int o = tid >> 2, q = tid & 3;
    bf16x8 t0 = *(const bf16x8*)(&ht_tile[o * 66 + q * 16]);
    bf16x8 t1 = *(const bf16x8*)(&ht_tile[o * 66 + q * 16 + 8]);
    __hip_bfloat16* dst = hT + (size_t)(hd * FOUT + o) * NROW + n0 + q * 16;
    *(bf16x8*)(dst)     = t0;
    *(bf16x8*)(dst + 8) = t1;
  }
}

// ---------------------------------------------------------------------------
// K2: adj -> bitmasks mw[w][n].  Block = 16 rows x 2048-col chunk.
// Loads: 16B/lane coalesced, 2-row pipeline. Lane->word bpermute transpose
// (mapping verified in R5). Stores coalesced via padded LDS tile [16n][65w].
// ---------------------------------------------------------------------------
__global__ __launch_bounds__(256) void mask_build(
    const int* __restrict__ adj, unsigned int* __restrict__ mw)
{
  const int tid = threadIdx.x;
  const int wid = tid >> 6, lane = tid & 63;
  const int rg = blockIdx.x >> 2, c = blockIdx.x & 3;
  const int n0 = rg * 16;
  const int bpbase = (lane & 7) << 5;      // source lane 8*(l&7)
  const int sh = (lane >> 3) << 2;         // nibble select

  __shared__ unsigned int tile[16][65];

  const int row0 = n0 + wid * 4;
  const i32x4* ap0 = (const i32x4*)(adj + (size_t)row0 * NROW) + c * 512;
  const size_t rstride = NROW / 4;         // i32x4 per row

  i32x4 va[8], vb[8];
#pragma unroll
  for (int j = 0; j < 8; ++j) va[j] = ap0[j * 64 + lane];

#pragma unroll
  for (int r = 0; r < 4; ++r) {
    // prefetch next row while packing this one
    if (r + 1 < 4) {
#pragma unroll
      for (int j = 0; j < 8; ++j)
        vb[j] = ap0[(r + 1) * rstride + j * 64 + lane];
    }
    unsigned nibs = 0;
#pragma unroll
    for (int j = 0; j < 8; ++j) {
      unsigned nib = min((unsigned)va[j][0], 1u)
                   | (min((unsigned)va[j][1], 1u) << 1)
                   | (min((unsigned)va[j][2], 1u) << 2)
                   | (min((unsigned)va[j][3], 1u) << 3);
      nibs |= nib << (4 * j);
    }
    unsigned w = 0;
#pragma unroll
    for (int t = 0; t < 8; ++t) {
      unsigned bp = (unsigned)__builtin_amdgcn_ds_bpermute(bpbase + 4 * t,
                                                           (int)nibs);
      w |= ((bp >> sh) & 0xFu) << (4 * t);
    }
    tile[wid * 4 + r][lane] = w;
    if (r + 1 < 4) {
#pragma unroll
      for (int j = 0; j < 8; ++j) va[j] = vb[j];
    }
  }
  __syncthreads();

  // store: n varies across lanes -> 64B segments
  const int nl = tid & 15, wq = tid >> 4;
#pragma unroll
  for (int j = 0; j < 4; ++j) {
    const int w = wq + 16 * j;
    mw[(size_t)(c * 64 + w) * NROW + n0 + nl] = tile[nl][w];
  }
}

// ---------------------------------------------------------------------------
// K3: attention partials. All inner-loop operands LDS/reg-resident:
//   E2/D2 chunk tables in LDS; mask words in registers per 8-iter segment;
//   hT tile [64o][64m] XOR-swizzled LDS, double-buffered, reg-prefetched.
// Block = 4 waves, same head, 64 rows. 1 barrier/iter.
// ---------------------------------------------------------------------------
template <int S>
__global__ __launch_bounds__(256, 4) void gat_attn(
    const unsigned int* __restrict__ mw, const __hip_bfloat16* __restrict__ hTg,
    const float* __restrict__ f1, const float* __restrict__ E2g,
    const float* __restrict__ D2g, float* __restrict__ part)
{
  constexpr int MCH = NROW / S;
  constexpr int NSEG = MCH / 64 / 8;
  const int tid = threadIdx.x;
  const int wid = tid >> 6, lane = tid & 63;
  const int il = lane & 15, kg = lane >> 4;

  const int nwg = S * NHEAD * 128;
  const int bid = (blockIdx.x & 7) * (nwg >> 3) + (blockIdx.x >> 3);
  const int rg = bid & 127;
  const int hd = (bid >> 7) & 3;
  const int mc = bid >> 9;
  const int n0 = rg * 64;
  const int n  = n0 + wid * 16 + il;
  const int mbase = mc * MCH;

  __shared__ __align__(16) __hip_bfloat16 lds[2][64 * 64];
  __shared__ __align__(16) float lds_e[MCH];
  __shared__ __align__(16) float lds_d[MCH];

  const float f1v = f1[hd * NROW + n];
  const float E1  = __builtin_amdgcn_exp2f(f1v);
  const float D1  = __builtin_amdgcn_exp2f(0.2f * f1v);
  const float iE1 = __builtin_amdgcn_exp2f(-f1v);

  const float* E2p = E2g + hd * NROW + mbase;
  const float* D2p = D2g + hd * NROW + mbase;
  const unsigned int* mwp = mw + (size_t)(mc * (MCH / 32)) * NROW + n;

  const int so = tid >> 2, sq = tid & 3;
  const __hip_bfloat16* hs = hTg + (hd * FOUT + so) * NROW + mbase + sq * 16;
  const int w0off = so * 64 + ((2 * sq)     ^ (so & 7)) * 8;
  const int w1off = so * 64 + ((2 * sq + 1) ^ (so & 7)) * 8;

  f32x4 acc[5];
#pragma unroll
  for (int c = 0; c < 5; ++c) { f32x4 z = {0.f,0.f,0.f,0.f}; acc[c] = z; }

  bf16x8 ones;
#pragma unroll
  for (int e = 0; e < 8; ++e) ones[e] = (__bf16)1.0f;

#pragma unroll
  for (int q = 0; q < MCH / 1024; ++q) {
    int idx = (q * 256 + tid) * 4;
    *(f32x4*)(&lds_e[idx]) = *(const f32x4*)(E2p + idx);
    *(f32x4*)(&lds_d[idx]) = *(const f32x4*)(D2p + idx);
  }
  {
    bf16x8 s0 = *(const bf16x8*)(hs);
    bf16x8 s1 = *(const bf16x8*)(hs + 8);
    *(bf16x8*)(&lds[0][w0off]) = s0;
    *(bf16x8*)(&lds[0][w1off]) = s1;
  }
  __syncthreads();

  int tb = 0;
  for (int seg = 0; seg < NSEG; ++seg) {
    unsigned int mreg[16];
#pragma unroll
    for (int j = 0; j < 16; ++j) mreg[j] = mwp[j * NROW];
    mwp += 16 * (size_t)NROW;

#pragma unroll
    for (int it2 = 0; it2 < 8; ++it2) {
      const int cur = (seg * 8 + it2) & 1;
      const bool more = (seg < NSEG - 1) || (it2 < 7);
      bf16x8 s0n, s1n;
      if (more) {                             // T14: issue next-tile loads early
        s0n = *(const bf16x8*)(hs + 64);
        s1n = *(const bf16x8*)(hs + 64 + 8);
      }

#pragma unroll
      for (int ks = 0; ks < 2; ++ks) {
        unsigned int mvs = mreg[it2 * 2 + ks] >> (kg * 8);
        const int mof = tb + it2 * 64 + ks * 32 + kg * 8;
        f32x4 e2l = *(const f32x4*)(&lds_e[mof]);
        f32x4 e2h = *(const f32x4*)(&lds_e[mof + 4]);
        f32x4 d2l = *(const f32x4*)(&lds_d[mof]);
        f32x4 d2h = *(const f32x4*)(&lds_d[mof + 4]);

        bf16x8 afr[4];
#pragma unroll
        for (int c = 0; c < 4; ++c) {
          const int row = c * 16 + il;
          afr[c] = *(const bf16x8*)(
              &lds[cur][row * 64 + ((ks * 4 + kg) ^ (il & 7)) * 8]);
        }

        float p[8];
#pragma unroll
        for (int e = 0; e < 8; ++e) {
          float E2v = (e < 4) ? e2l[e] : e2h[e - 4];
          float D2v = (e < 4) ? d2l[e] : d2h[e - 4];
          bool neg = E2v < iE1;                       // s < 0
          float c2 = neg ? D2v : E2v;
          float c1 = neg ? D1 : E1;
          float q = c1 * c2;
          int msk = ((int)(mvs << (31 - e))) >> 31;   // bit e -> 0 / -1
          p[e] = __uint_as_float(__float_as_uint(q) & (unsigned)msk);
        }
        bf16x8 pb;
#pragma unroll
        for (int e = 0; e < 8; ++e) pb[e] = (__bf16)p[e];

#pragma unroll
        for (int c = 0; c < 4; ++c)
          acc[c] = __builtin_amdgcn_mfma_f32_16x16x32_bf16(afr[c], pb, acc[c], 0, 0, 0);
        acc[4] = __builtin_amdgcn_mfma_f32_16x16x32_bf16(ones, pb, acc[4], 0, 0, 0);
      }

      if (more) {
        *(bf16x8*)(&lds[cur ^ 1][w0off]) = s0n;
        *(bf16x8*)(&lds[cur ^ 1][w1off]) = s1n;
        __syncthreads();
      }
      hs += 64;
    }
    tb += 512;
  }

  float* pp = part + ((size_t)((mc * NHEAD + hd) * NROW + n)) * 68;
#pragma unroll
  for (int c = 0; c < 4; ++c)
    *(f32x4*)(pp + c * 16 + kg * 4) = acc[c];
  if (kg == 0) pp[64] = acc[4][0];
}

// ---------------------------------------------------------------------------
// K4: combine S partial slices, divide, sigmoid, write out.
// ---------------------------------------------------------------------------
__global__ __launch_bounds__(256) void gat_comb(
    const float* __restrict__ part, float* __restrict__ out, int S)
{
  int flat = blockIdx.x * 256 + threadIdx.x;
  int n = flat >> 6, c4 = flat & 63;
  int hd = c4 >> 4, o4 = (c4 & 15) * 4;
  f32x4 num = {0.f,0.f,0.f,0.f};
  float L = 0.f;
  for (int s = 0; s < S; ++s) {
    const float* pp = part + ((size_t)((s * NHEAD + hd) * NROW + n)) * 68;
    f32x4 v = *(const f32x4*)(pp + o4);
    num += v;
    L += pp[64];
  }
  float invL = 1.0f / L;
  f32x4 r;
#pragma unroll
  for (int j = 0; j < 4; ++j)
    r[j] = 1.0f / (1.0f + __builtin_amdgcn_exp2f(-num[j] * invL * LOG2E));
  *(f32x4*)(out + (size_t)n * (NHEAD * FOUT) + hd * FOUT + o4) = r;
}

extern "C" void kernel_launch(void* const* d_in, const int* in_sizes, int n_in,
                              void* d_out, int out_size, void* d_ws, size_t ws_size,
                              hipStream_t stream) {
  const float* x   = (const float*)d_in[0];
  const int*   adj = (const int*)d_in[1];
  const float* W   = (const float*)d_in[2];
  const float* a1  = (const float*)d_in[3];
  const float* a2  = (const float*)d_in[4];
  float* out = (float*)d_out;

  char* ws = (char*)d_ws;
  const size_t WT_OFF = 0;
  const size_t HT_OFF = WT_OFF + (size_t)NHEAD * FOUT * FIN * 2;     // 256 KB
  const size_t F1_OFF = HT_OFF + (size_t)NHEAD * FOUT * NROW * 2;    // 4 MB
  const size_t E2_OFF = F1_OFF + (size_t)NHEAD * NROW * 4;
  const size_t D2_OFF = E2_OFF + (size_t)NHEAD * NROW * 4;
  const size_t MW_OFF = D2_OFF + (size_t)NHEAD * NROW * 4;
  const size_t PT_OFF = MW_OFF + (size_t)(NROW / 32) * NROW * 4;     // +8 MB
  const size_t PART_SLICE = (size_t)NHEAD * NROW * 68 * 4;           // 8.9 MB

  int S = (ws_size >= PT_OFF + 4 * PART_SLICE) ? 4
        : (ws_size >= PT_OFF + 2 * PART_SLICE) ? 2 : 1;

  __hip_bfloat16* WT = (__hip_bfloat16*)(ws + WT_OFF);
  __hip_bfloat16* hT = (__hip_bfloat16*)(ws + HT_OFF);
  float* f1 = (float*)(ws + F1_OFF);
  float* E2 = (float*)(ws + E2_OFF);
  float* D2 = (float*)(ws + D2_OFF);
  unsigned int* mw = (unsigned int*)(ws + MW_OFF);
  float* part = (float*)(ws + PT_OFF);

  wt_build<<<8, 256, 0, stream>>>(W, WT);
  gat_proj<<<NHEAD * (NROW / 64), 256, 0, stream>>>(x, WT, a1, a2, hT, f1, E2, D2);
  mask_build<<<(NROW / 16) * 4, 256, 0, stream>>>(adj, mw);
  if (S == 4)
    gat_attn<4><<<4 * NHEAD * 128, 256, 0, stream>>>(mw, hT, f1, E2, D2, part);
  else if (S == 2)
    gat_attn<2><<<2 * NHEAD * 128, 256, 0, stream>>>(mw, hT, f1, E2, D2, part);
  else
    gat_attn<1><<<1 * NHEAD * 128, 256, 0, stream>>>(mw, hT, f1, E2, D2, part);
  gat_comb<<<NROW * NHEAD * FOUT / 4 / 256, 256, 0, stream>>>(part, out, S);
}